// Round 4
// baseline (459.543 us; speedup 1.0000x reference)
//
#include <hip/hip_runtime.h>

typedef float f32x4 __attribute__((ext_vector_type(4)));
typedef _Float16 half8 __attribute__((ext_vector_type(8)));
typedef unsigned int u32x2 __attribute__((ext_vector_type(2)));

#define DEV __device__ __forceinline__

constexpr int B_ = 8, H_ = 8, N_ = 784, D_ = 96, C_ = 768, NP_ = 800;
constexpr int NT = 49;                               // 16-row tiles across N
constexpr float SCALE_ = 0.10206207261596575f;       // 96^-0.5
constexpr float INV_N = 1.0f / 784.0f;
constexpr int GSUB = 7;                              // gstat row-tile subsample stride

// ---- workspace layout (bytes) ----
constexpr size_t SZ_QKH  = (size_t)B_*H_*N_*D_*2;    // 9,633,792 (fp16)
constexpr size_t OFF_QH  = 0;
constexpr size_t OFF_KH  = OFF_QH + SZ_QKH;
constexpr size_t OFF_VHT = OFF_KH + SZ_QKH;          // vh transposed (B,H,D,NP) fp16
constexpr size_t SZ_VHT  = (size_t)B_*H_*D_*NP_*2;   // 9,830,400
constexpr size_t OFF_Z   = OFF_VHT + SZ_VHT;         // (B,H,N) f32 softmax denominators
constexpr size_t SZ_Z    = (size_t)B_*H_*N_*4;       // 200,704
constexpr size_t OFF_G   = OFF_Z + SZ_Z;             // 36 pairs x 8 banks f32
constexpr size_t SZ_G    = 36*8*4;
constexpr size_t OFF_COEF= OFF_G + 2048;             // W'[64] + c[8] f32
constexpr size_t OFF_SV  = OFF_COEF + 2048;          // (B,H,D) f32 V column sums
constexpr size_t SZ_SV   = (size_t)B_*H_*D_*4;       // 24,576
constexpr size_t OFF_AT  = OFF_SV + SZ_SV;           // centered-mixed attn, fp16, PV-A-frag tiled
constexpr size_t SZ_AT   = (size_t)B_*H_*NT*25*64*8*2; // 80,281,600
constexpr size_t OFF_X   = OFF_AT + SZ_AT;           // (B,N,C) fp16
constexpr size_t SZ_X    = (size_t)B_*N_*C_*2;
constexpr size_t OFF_WPB = OFF_X + SZ_X;             // Wp fp16 (C,C)
constexpr size_t WS_NEED = OFF_WPB + (size_t)C_*C_*2;

DEV unsigned short f2h(float f) {
  _Float16 h = (_Float16)f; unsigned short u; __builtin_memcpy(&u, &h, 2); return u;
}

DEV f32x4 MF(half8 a, half8 b, f32x4 c) {
  return __builtin_amdgcn_mfma_f32_16x16x32_f16(a, b, c, 0, 0, 0);
}

// ---------------- K1: 3x3 conv over (3,16,16) token patches -> head layouts (fp16) ------------
__global__ __launch_bounds__(256) void k_conv(
    const float* __restrict__ q, const float* __restrict__ k, const float* __restrict__ v,
    const float* __restrict__ Wq, const float* __restrict__ Wk, const float* __restrict__ Wv,
    _Float16* __restrict__ qh, _Float16* __restrict__ kh, _Float16* __restrict__ vht)
{
  __shared__ float sm[3][18][18];
  const int t = blockIdx.y;
  const int bn = blockIdx.x;
  const int b = bn / N_, n = bn % N_;
  const float* src = (t == 0) ? q : (t == 1) ? k : v;
  const float* W   = (t == 0) ? Wq : (t == 1) ? Wk : Wv;
  const int tid = threadIdx.x;
  for (int i = tid; i < 3*18*18; i += 256) ((float*)sm)[i] = 0.0f;
  __syncthreads();
  for (int i = tid; i < 768; i += 256) {
    int ch = i >> 8, rr = (i >> 4) & 15, cc = i & 15;
    sm[ch][rr+1][cc+1] = src[(size_t)bn*768 + i];
  }
  __syncthreads();
  const int r = tid >> 4, c = tid & 15;
  #pragma unroll
  for (int oc = 0; oc < 3; ++oc) {
    float acc = 0.0f;
    #pragma unroll
    for (int ic = 0; ic < 3; ++ic)
      #pragma unroll
      for (int dr = 0; dr < 3; ++dr)
        #pragma unroll
        for (int dc = 0; dc < 3; ++dc)
          acc += sm[ic][r+dr][c+dc] * W[((oc*3+ic)*3+dr)*3+dc];
    const int cidx = oc*256 + tid;
    const int h = cidx / 96, d = cidx % 96;
    if (t == 0) {
      qh[((size_t)(b*8+h)*N_ + n)*96 + d] = (_Float16)(acc * SCALE_);  // fold softmax scale
    } else if (t == 1) {
      kh[((size_t)(b*8+h)*N_ + n)*96 + d] = (_Float16)acc;
    } else {
      vht[((size_t)(b*8+h)*96 + d)*NP_ + n] = (_Float16)acc;           // transposed for PV B-op
    }
  }
}

// ---------------- K1b: cast Wp to fp16 ----------------
__global__ __launch_bounds__(256) void k_cast(const float* __restrict__ wp, _Float16* __restrict__ wpb) {
  const int i = (blockIdx.x*256 + threadIdx.x)*4;
  #pragma unroll
  for (int j = 0; j < 4; ++j) wpb[i+j] = (_Float16)wp[i+j];
}

// ---------------- K1c: V column sums SV[b,h,d] = sum_m vht[b,h,d,m] ----------------
__global__ __launch_bounds__(256) void k_vsum(const _Float16* __restrict__ vht, float* __restrict__ SV) {
  const int bh = blockIdx.x;
  const int tid = threadIdx.x, w = tid >> 6, lane = tid & 63;
  for (int d = w; d < 96; d += 4) {
    const _Float16* p = vht + ((size_t)bh*96 + d)*NP_;
    float s = 0.f;
    for (int i = lane; i < NP_; i += 64) s += (float)p[i];
    #pragma unroll
    for (int m = 1; m < 64; m <<= 1) s += __shfl_xor(s, m);
    if (lane == 0) SV[bh*96 + d] = s;
  }
}

// ---------------- K2a: softmax denominators via swapped QK^T (no LDS, no barriers) -----------
__global__ __launch_bounds__(448) void k_zsum(const _Float16* __restrict__ qh,
    const _Float16* __restrict__ kh, float* __restrict__ Z)
{
  const int b = blockIdx.x, ntg = blockIdx.y, s = blockIdx.z;
  const int tid = threadIdx.x, w = tid >> 6, lane = tid & 63, g = lane >> 4, ci = lane & 15;
  const int nt = ntg*7 + w;                          // 7 waves x 7 groups = 49
  #pragma unroll 1
  for (int h = 0; h < 8; ++h) {
    const _Float16* qp = qh + ((size_t)(b*8+h)*N_ + nt*16 + ci)*96 + g*8;
    half8 q0 = *(const half8*)qp, q1 = *(const half8*)(qp+32), q2 = *(const half8*)(qp+64);
    float zp = 0.f;
    for (int mt = s; mt < NT; mt += 4) {
      const _Float16* kp = kh + ((size_t)(b*8+h)*N_ + mt*16 + ci)*96 + g*8;
      half8 k0 = *(const half8*)kp, k1 = *(const half8*)(kp+32), k2 = *(const half8*)(kp+64);
      f32x4 acc = {0.f,0.f,0.f,0.f};
      acc = MF(k0,q0,acc); acc = MF(k1,q1,acc); acc = MF(k2,q2,acc);   // S[m][n=ci]
      zp += __expf(acc.x) + __expf(acc.y) + __expf(acc.z) + __expf(acc.w);
    }
    zp += __shfl_xor(zp, 16); zp += __shfl_xor(zp, 32);
    if (lane < 16) atomicAdd(&Z[(size_t)(b*8+h)*N_ + nt*16 + lane], zp);
  }
}

// ---------------- K2b: centered cross-head second moments G'[36], row-subsampled -------------
__global__ __launch_bounds__(256) void k_gstat(const _Float16* __restrict__ qh,
    const _Float16* __restrict__ kh, const float* __restrict__ Z, float* __restrict__ G)
{
  __shared__ float gred[4][36];
  const int rt = blockIdx.x * GSUB, b = blockIdx.y;
  const int tid = threadIdx.x, w = tid >> 6, lane = tid & 63, g = lane >> 4, ci = lane & 15;
  float rZ[8][4];
  #pragma unroll
  for (int h = 0; h < 8; ++h)
    #pragma unroll
    for (int r = 0; r < 4; ++r)
      rZ[h][r] = 1.0f / Z[(size_t)(b*8+h)*N_ + rt*16 + g*4 + r];
  float Gacc[36];
  #pragma unroll
  for (int i = 0; i < 36; ++i) Gacc[i] = 0.f;
  for (int mt = w; mt < NT; mt += 4) {
    float cen[8][4];
    #pragma unroll
    for (int h = 0; h < 8; ++h) {
      const _Float16* qp = qh + ((size_t)(b*8+h)*N_ + rt*16 + ci)*96 + g*8;
      half8 a0 = *(const half8*)qp, a1 = *(const half8*)(qp+32), a2 = *(const half8*)(qp+64);
      const _Float16* kp = kh + ((size_t)(b*8+h)*N_ + mt*16 + ci)*96 + g*8;
      half8 b0 = *(const half8*)kp, b1 = *(const half8*)(kp+32), b2 = *(const half8*)(kp+64);
      f32x4 acc = {0.f,0.f,0.f,0.f};
      acc = MF(a0,b0,acc); acc = MF(a1,b1,acc); acc = MF(a2,b2,acc);
      cen[h][0] = __expf(acc.x)*rZ[h][0] - INV_N;
      cen[h][1] = __expf(acc.y)*rZ[h][1] - INV_N;
      cen[h][2] = __expf(acc.z)*rZ[h][2] - INV_N;
      cen[h][3] = __expf(acc.w)*rZ[h][3] - INV_N;
    }
    int idx = 0;
    #pragma unroll
    for (int h1 = 0; h1 < 8; ++h1)
      #pragma unroll
      for (int h2 = h1; h2 < 8; ++h2) {
        Gacc[idx] += cen[h1][0]*cen[h2][0] + cen[h1][1]*cen[h2][1]
                   + cen[h1][2]*cen[h2][2] + cen[h1][3]*cen[h2][3];
        ++idx;
      }
  }
  #pragma unroll
  for (int i = 0; i < 36; ++i) {
    float vv = Gacc[i];
    #pragma unroll
    for (int m = 32; m >= 1; m >>= 1) vv += __shfl_xor(vv, m);
    Gacc[i] = vv;
  }
  if (lane == 0) {
    #pragma unroll
    for (int i = 0; i < 36; ++i) gred[w][i] = Gacc[i];
  }
  __syncthreads();
  if (tid < 36) {
    float s = gred[0][tid] + gred[1][tid] + gred[2][tid] + gred[3][tid];
    atomicAdd(&G[tid*8 + (blockIdx.x & 7)], s);
  }
}

// ---------------- K3: finalize BN-folded mixing coefficients ----------------
__global__ __launch_bounds__(64) void k_coef(const float* __restrict__ G,
    const float* __restrict__ Wre, const float* __restrict__ bre,
    const float* __restrict__ gamma, const float* __restrict__ beta,
    float* __restrict__ coef)
{
  const int o = threadIdx.x;
  if (o >= 8) return;
  float Gs[36];
  for (int i = 0; i < 36; ++i) {
    float s = 0;
    for (int j = 0; j < 8; ++j) s += G[i*8+j];
    Gs[i] = s;
  }
  float vs = 0; int idx = 0;
  for (int h1 = 0; h1 < 8; ++h1)
    for (int h2 = h1; h2 < 8; ++h2) {
      float ww = Wre[o*8+h1] * Wre[o*8+h2] * ((h1 == h2) ? 1.0f : 2.0f);
      vs += ww * Gs[idx]; ++idx;
    }
  const float var = vs * ((float)GSUB / ((float)B_ * (float)N_ * (float)N_));
  const float scale = gamma[o] * rsqrtf(var + 1e-5f);
  for (int h = 0; h < 8; ++h) coef[o*8+h] = scale * Wre[o*8+h];
  (void)bre;  // cancels against the BN mean
}

// ---------------- K4: swapped QK^T -> p -> centered mix -> store fp16 A-frag tiles -----------
// stored value: fl[o][n][m] = sum_h W'[o,h] * (p_h[n][m] - 1/N)   (attnM = fl + beta_o)
__global__ __launch_bounds__(256) void k_qkmix(const _Float16* __restrict__ qh,
    const _Float16* __restrict__ kh, const float* __restrict__ Z,
    const float* __restrict__ coef, unsigned short* __restrict__ at)
{
  const int b = blockIdx.x, ntg = blockIdx.y, s = blockIdx.z;
  const int tid = threadIdx.x, w = tid >> 6, lane = tid & 63, g = lane >> 4, ci = lane & 15;
  const int nt = ntg*4 + w;
  if (nt >= NT) return;
  float m0[8];
  #pragma unroll
  for (int o = 0; o < 8; ++o) {
    float sw = 0.f;
    #pragma unroll
    for (int h = 0; h < 8; ++h) sw += coef[o*8+h];
    m0[o] = -INV_N * sw;
  }
  #pragma unroll 1
  for (int mc = s; mc < 25; mc += 4) {
    float mix[8][2][4];
    const bool t1ok = (mc*2+1 < NT);
    #pragma unroll
    for (int o = 0; o < 8; ++o)
      #pragma unroll
      for (int r = 0; r < 4; ++r) { mix[o][0][r] = m0[o]; mix[o][1][r] = t1ok ? m0[o] : 0.f; }
    #pragma unroll 1
    for (int h = 0; h < 8; ++h) {
      const float rz = 1.0f / Z[(size_t)(b*8+h)*N_ + nt*16 + ci];
      const _Float16* qp = qh + ((size_t)(b*8+h)*N_ + nt*16 + ci)*96 + g*8;
      half8 q0 = *(const half8*)qp, q1 = *(const half8*)(qp+32), q2 = *(const half8*)(qp+64);
      float e[2][4];
      #pragma unroll
      for (int t = 0; t < 2; ++t) {
        const int mt = mc*2 + t;
        if (mt < NT) {
          const _Float16* kp = kh + ((size_t)(b*8+h)*N_ + mt*16 + ci)*96 + g*8;
          half8 k0 = *(const half8*)kp, k1 = *(const half8*)(kp+32), k2 = *(const half8*)(kp+64);
          f32x4 acc = {0.f,0.f,0.f,0.f};
          acc = MF(k0,q0,acc); acc = MF(k1,q1,acc); acc = MF(k2,q2,acc);  // S[m][n=ci]
          e[t][0] = __expf(acc.x)*rz; e[t][1] = __expf(acc.y)*rz;
          e[t][2] = __expf(acc.z)*rz; e[t][3] = __expf(acc.w)*rz;
        } else {
          e[t][0] = e[t][1] = e[t][2] = e[t][3] = 0.f;
        }
      }
      #pragma unroll
      for (int o = 0; o < 8; ++o) {
        const float wv = coef[o*8+h];
        #pragma unroll
        for (int t = 0; t < 2; ++t) {
          mix[o][t][0] += wv*e[t][0]; mix[o][t][1] += wv*e[t][1];
          mix[o][t][2] += wv*e[t][2]; mix[o][t][3] += wv*e[t][3];
        }
      }
    }
    // store: PV-A-frag layout; lane(g,ci) holds m' = t*16 + g*4 + r -> slot lane' = m'>>3
    #pragma unroll
    for (int o = 0; o < 8; ++o) {
      const size_t base = (((size_t)(b*8+o)*NT + nt)*25 + mc)*512;   // u16 units
      #pragma unroll
      for (int t = 0; t < 2; ++t) {
        u32x2 dv;
        dv.x = (unsigned)f2h(mix[o][t][0]) | ((unsigned)f2h(mix[o][t][1]) << 16);
        dv.y = (unsigned)f2h(mix[o][t][2]) | ((unsigned)f2h(mix[o][t][3]) << 16);
        const int idx = ((t*2 + (g>>1))*16 + ci)*8 + (g&1)*4;
        *(u32x2*)(at + base + idx) = dv;
      }
    }
  }
}

// ---------------- K5: pure PV GEMM per (b,o): x = fl @ V + beta_o * colsum(V) ----------------
__global__ __launch_bounds__(448) void k_pv(const unsigned short* __restrict__ at,
    const _Float16* __restrict__ vht, const float* __restrict__ SV,
    const float* __restrict__ beta, _Float16* __restrict__ x)
{
  const int b = blockIdx.x, o = blockIdx.y, ntg = blockIdx.z;
  const int tid = threadIdx.x, w = tid >> 6, lane = tid & 63, g = lane >> 4, ci = lane & 15;
  const int nt = ntg*7 + w;
  f32x4 acc[6];
  #pragma unroll
  for (int dt = 0; dt < 6; ++dt) acc[dt] = (f32x4){0.f,0.f,0.f,0.f};
  const unsigned short* ab = at + (((size_t)(b*8+o)*NT + nt)*25)*512 + lane*8;
  const _Float16* vb = vht + ((size_t)(b*8+o)*96 + ci)*NP_ + g*8;
  #pragma unroll 2
  for (int mc = 0; mc < 25; ++mc) {
    half8 a = *(const half8*)(ab + mc*512);
    #pragma unroll
    for (int dt = 0; dt < 6; ++dt) {
      half8 vv = *(const half8*)(vb + (size_t)dt*16*NP_ + mc*32);
      acc[dt] = MF(a, vv, acc[dt]);
    }
  }
  const float bo = beta[o];
  #pragma unroll
  for (int dt = 0; dt < 6; ++dt) {
    const float bsv = bo * SV[(size_t)(b*8+o)*96 + dt*16 + ci];
    #pragma unroll
    for (int r = 0; r < 4; ++r)
      x[((size_t)b*N_ + nt*16 + g*4 + r)*C_ + o*96 + dt*16 + ci] = (_Float16)(acc[dt][r] + bsv);
  }
}

// ---------------- K6: output projection x @ Wp^T + bp (fp16 in, fp32 out) --------------------
__global__ __launch_bounds__(256) void k_proj(const _Float16* __restrict__ x,
    const _Float16* __restrict__ wpb, const float* __restrict__ bp, float* __restrict__ out)
{
  const int rb = blockIdx.x, cb = blockIdx.y;
  const int tid = threadIdx.x, w = tid >> 6, lane = tid & 63, g = lane >> 4, ci = lane & 15;
  const int row0 = rb*64 + w*16;
  const int col0 = cb*128;
  f32x4 acc[8];
  #pragma unroll
  for (int ct = 0; ct < 8; ++ct) acc[ct] = (f32x4){0.f,0.f,0.f,0.f};
  for (int k0 = 0; k0 < 768; k0 += 32) {
    half8 a = *(const half8*)(x + (size_t)(row0+ci)*768 + k0 + g*8);
    #pragma unroll
    for (int ct = 0; ct < 8; ++ct) {
      half8 bb = *(const half8*)(wpb + (size_t)(col0+ct*16+ci)*768 + k0 + g*8);
      acc[ct] = MF(a, bb, acc[ct]);
    }
  }
  #pragma unroll
  for (int ct = 0; ct < 8; ++ct) {
    const int c = col0 + ct*16 + ci;
    const float bias = bp[c];
    #pragma unroll
    for (int r = 0; r < 4; ++r)
      out[(size_t)(row0 + g*4 + r)*768 + c] = acc[ct][r] + bias;
  }
}

extern "C" void kernel_launch(void* const* d_in, const int* in_sizes, int n_in,
                              void* d_out, int out_size, void* d_ws, size_t ws_size,
                              hipStream_t stream) {
  const float* q     = (const float*)d_in[0];
  const float* k     = (const float*)d_in[1];
  const float* v     = (const float*)d_in[2];
  const float* Wq    = (const float*)d_in[3];
  const float* Wk    = (const float*)d_in[4];
  const float* Wv    = (const float*)d_in[5];
  const float* Wre   = (const float*)d_in[6];
  const float* bre   = (const float*)d_in[7];
  const float* gamma = (const float*)d_in[8];
  const float* beta  = (const float*)d_in[9];
  const float* Wp    = (const float*)d_in[10];
  const float* bp    = (const float*)d_in[11];
  if (ws_size < WS_NEED) return;                     // fail loudly if scratch too small
  char* ws = (char*)d_ws;
  _Float16* qh  = (_Float16*)(ws + OFF_QH);
  _Float16* kh  = (_Float16*)(ws + OFF_KH);
  _Float16* vht = (_Float16*)(ws + OFF_VHT);
  float* Zb   = (float*)(ws + OFF_Z);
  float* G    = (float*)(ws + OFF_G);
  float* coef = (float*)(ws + OFF_COEF);
  float* SV   = (float*)(ws + OFF_SV);
  unsigned short* at = (unsigned short*)(ws + OFF_AT);
  _Float16* xb  = (_Float16*)(ws + OFF_X);
  _Float16* wpb = (_Float16*)(ws + OFF_WPB);

  hipMemsetAsync(ws + OFF_G, 0, SZ_G, stream);
  hipMemsetAsync(ws + OFF_Z, 0, SZ_Z, stream);
  hipMemsetAsync(ws + OFF_VHT, 0, SZ_VHT, stream);   // zero m-padding (feeds SV + PV tails)

  k_conv<<<dim3(B_*N_, 3), 256, 0, stream>>>(q, k, v, Wq, Wk, Wv, qh, kh, vht);
  k_cast<<<dim3(576), 256, 0, stream>>>(Wp, wpb);
  k_vsum<<<dim3(64), 256, 0, stream>>>(vht, SV);
  k_zsum<<<dim3(B_, 7, 4), 448, 0, stream>>>(qh, kh, Zb);
  k_gstat<<<dim3(7, B_), 256, 0, stream>>>(qh, kh, Zb, G);
  k_coef<<<dim3(1), 64, 0, stream>>>(G, Wre, bre, gamma, beta, coef);
  k_qkmix<<<dim3(B_, 13, 4), 256, 0, stream>>>(qh, kh, Zb, coef, at);
  k_pv<<<dim3(B_, 8, 7), 448, 0, stream>>>(at, vht, SV, beta, xb);
  k_proj<<<dim3(98, 6), 256, 0, stream>>>(xb, wpb, bp, (float*)d_out);
}